// Round 1
// baseline (15913.148 us; speedup 1.0000x reference)
//
#include <hip/hip_runtime.h>
#include <hip/hip_bf16.h>

#define BB 8
#define TT 2048
#define DD 512
#define GG 64   // slabs per batch (8 rows each)

typedef unsigned short u16;
typedef unsigned int u32;

__device__ __forceinline__ float bf2f(u32 h) { return __uint_as_float(h << 16); }
__device__ __forceinline__ u16 f2bf(float f) {
    u32 u = __float_as_uint(f);
    u += 0x7fffu + ((u >> 16) & 1u);
    return (u16)(u >> 16);
}
__device__ __forceinline__ float wred64(float v) {
    #pragma unroll
    for (int off = 32; off; off >>= 1) v += __shfl_xor(v, off);
    return v;
}
__device__ __forceinline__ void unpack8(uint4 r, float* f) {
    f[0] = bf2f(r.x & 0xffff); f[1] = bf2f(r.x >> 16);
    f[2] = bf2f(r.y & 0xffff); f[3] = bf2f(r.y >> 16);
    f[4] = bf2f(r.z & 0xffff); f[5] = bf2f(r.z >> 16);
    f[6] = bf2f(r.w & 0xffff); f[7] = bf2f(r.w >> 16);
}

// C[m][n] = (sum_k X[m][k]*W[n][k] + bias[n]) * outscale ; N = 512 fixed
template<int IN_BF, int OUT_BF>
__global__ __launch_bounds__(256)
void gemm_xwT(const void* __restrict__ Xin, const float* __restrict__ W,
              const float* __restrict__ bias, void* __restrict__ Cout,
              const int K, const float outscale)
{
    __shared__ float Xs[32][68];
    __shared__ float Ws[32][68];
    const int m0 = blockIdx.x * 64, n0 = blockIdx.y * 64;
    const int tid = threadIdx.x;
    const int tx = tid & 15, ty = tid >> 4;
    float acc[4][4] = {};
    for (int k0 = 0; k0 < K; k0 += 32) {
        #pragma unroll
        for (int h = 0; h < 2; ++h) {
            const int f4 = tid + h * 256;
            const int r = f4 >> 3, c4 = f4 & 7;
            float v0, v1, v2, v3;
            if (IN_BF) {
                const u16* p = (const u16*)Xin + (size_t)(m0 + r) * K + k0 + c4 * 4;
                const uint2 raw = *(const uint2*)p;
                v0 = bf2f(raw.x & 0xffff); v1 = bf2f(raw.x >> 16);
                v2 = bf2f(raw.y & 0xffff); v3 = bf2f(raw.y >> 16);
            } else {
                const float4 raw = *(const float4*)((const float*)Xin + (size_t)(m0 + r) * K + k0 + c4 * 4);
                v0 = raw.x; v1 = raw.y; v2 = raw.z; v3 = raw.w;
            }
            Xs[c4 * 4 + 0][r] = v0; Xs[c4 * 4 + 1][r] = v1;
            Xs[c4 * 4 + 2][r] = v2; Xs[c4 * 4 + 3][r] = v3;
            const float4 wr = *(const float4*)(W + (size_t)(n0 + r) * K + k0 + c4 * 4);
            Ws[c4 * 4 + 0][r] = wr.x; Ws[c4 * 4 + 1][r] = wr.y;
            Ws[c4 * 4 + 2][r] = wr.z; Ws[c4 * 4 + 3][r] = wr.w;
        }
        __syncthreads();
        #pragma unroll
        for (int kk = 0; kk < 32; ++kk) {
            const float4 xa = *(const float4*)&Xs[kk][ty * 4];
            const float4 wb = *(const float4*)&Ws[kk][tx * 4];
            const float xv[4] = {xa.x, xa.y, xa.z, xa.w};
            const float wv[4] = {wb.x, wb.y, wb.z, wb.w};
            #pragma unroll
            for (int i = 0; i < 4; ++i)
                #pragma unroll
                for (int j = 0; j < 4; ++j)
                    acc[i][j] = fmaf(xv[i], wv[j], acc[i][j]);
        }
        __syncthreads();
    }
    #pragma unroll
    for (int i = 0; i < 4; ++i) {
        const int m = m0 + ty * 4 + i;
        #pragma unroll
        for (int j = 0; j < 4; ++j) {
            const int n = n0 + tx * 4 + j;
            const float val = (acc[i][j] + bias[n]) * outscale;
            if (OUT_BF) ((u16*)Cout)[(size_t)m * DD + n] = f2bf(val);
            else        ((float*)Cout)[(size_t)m * DD + n] = val;
        }
    }
}

// s_seq = sqrt(512) * sum(Q*U) ; Vn = V/(||V||+1e-6) in place (one wave per row)
__global__ __launch_bounds__(256)
void prep_kernel(const u16* __restrict__ Qb, const u16* __restrict__ Ub,
                 u16* __restrict__ Vb, float* __restrict__ sseq)
{
    const int lane = threadIdx.x & 63, wid = threadIdx.x >> 6;
    const int row = blockIdx.x * 4 + wid;
    const size_t base = (size_t)row * DD;
    const uint4 qr = *(const uint4*)(Qb + base + lane * 8);
    const uint4 ur = *(const uint4*)(Ub + base + lane * 8);
    const uint4 vr = *(const uint4*)(Vb + base + lane * 8);
    float q[8], u[8], v[8];
    unpack8(qr, q); unpack8(ur, u); unpack8(vr, v);
    float sd = 0.f, nv = 0.f;
    #pragma unroll
    for (int e = 0; e < 8; ++e) { sd = fmaf(q[e], u[e], sd); nv = fmaf(v[e], v[e], nv); }
    #pragma unroll
    for (int off = 32; off; off >>= 1) { sd += __shfl_xor(sd, off); nv += __shfl_xor(nv, off); }
    if (lane == 0) sseq[row] = sd * 22.627416997969522f;
    const float inv = 1.f / (sqrtf(nv) + 1e-6f);
    uint4 o;
    o.x = (u32)f2bf(v[0] * inv) | ((u32)f2bf(v[1] * inv) << 16);
    o.y = (u32)f2bf(v[2] * inv) | ((u32)f2bf(v[3] * inv) << 16);
    o.z = (u32)f2bf(v[4] * inv) | ((u32)f2bf(v[5] * inv) << 16);
    o.w = (u32)f2bf(v[6] * inv) | ((u32)f2bf(v[7] * inv) << 16);
    *(uint4*)(Vb + base + lane * 8) = o;
}

__global__ __launch_bounds__(256)
void init_kernel(float4* __restrict__ A4, float4* __restrict__ S4,
                 float* __restrict__ zbuf, const u16* __restrict__ Ub)
{
    const int gtid = blockIdx.x * 256 + threadIdx.x;
    const int N4 = BB * DD * DD / 4;
    for (int idx = gtid; idx < N4; idx += gridDim.x * 256) {
        const int e0 = idx << 2;
        const int r = (e0 >> 9) & 511;
        const int c = e0 & 511;
        float4 v;
        v.x = (c + 0 == r) ? 1.f : 0.f;
        v.y = (c + 1 == r) ? 1.f : 0.f;
        v.z = (c + 2 == r) ? 1.f : 0.f;
        v.w = (c + 3 == r) ? 1.f : 0.f;
        A4[idx] = v;
        S4[idx] = make_float4(0.f, 0.f, 0.f, 0.f);
    }
    if (gtid < BB * DD) {
        const int b = gtid >> 9, i = gtid & 511;
        zbuf[b * DD + i] = bf2f(Ub[(size_t)b * TT * DD + i]);  // z_0 = A_0 u_0 = u_0
    }
}

// One step of the scan. 512 blocks: (batch, slab of 8 rows). Kernel boundary = global sync.
// zbuf holds z_t = A_stored * u_t (double-buffered); the explosion-guard +1e-5*I is applied
// lazily: pend corrects z and is materialized onto A's diagonal in this step's pass.
__global__ __launch_bounds__(256)
void step_kernel(const int t,
    const u16* __restrict__ Qb, const u16* __restrict__ Ub, const u16* __restrict__ Vnb,
    const float* __restrict__ sseq,
    float* __restrict__ A, float* __restrict__ S,
    float* __restrict__ zbuf,  // [2][B][512]
    float* __restrict__ nrm,   // [2][2][B][GG]  (parity, {A,S}, b, slab)
    u16* __restrict__ Ob)
{
    __shared__ __align__(16) float zs[DD], us[DD], un[DD], qs[DD], al[DD];
    __shared__ float bc[8], rA[4], rS[4];
    const int blk = blockIdx.x;
    const int b = blk >> 6, slab = blk & 63;
    const int tid = threadIdx.x, lane = tid & 63, wid = tid >> 6;
    const int cur = t & 1, nxt = cur ^ 1;
    const size_t rowbase = ((size_t)b * TT + t) * DD;
    const int tn = (t + 1 < TT) ? (t + 1) : t;
    const size_t rowbaseN = ((size_t)b * TT + tn) * DD;

    float u_r[2], z_r[2];
    #pragma unroll
    for (int h = 0; h < 2; ++h) {
        const int i = tid + h * 256;
        const float uu = bf2f(Ub[rowbase + i]);
        us[i] = uu; u_r[h] = uu;
        qs[i] = bf2f(Qb[rowbase + i]);
        un[i] = bf2f(Ub[rowbaseN + i]);
        z_r[h] = zbuf[(size_t)cur * (BB * DD) + b * DD + i];
    }
    if (t > 0 && wid == 0) {
        float pa = nrm[((size_t)nxt * 2 + 0) * (BB * GG) + b * GG + lane];
        float ps = nrm[((size_t)nxt * 2 + 1) * (BB * GG) + b * GG + lane];
        pa = wred64(pa); ps = wred64(ps);
        if (lane == 0) { bc[0] = pa; bc[1] = ps; }
    }
    __syncthreads();
    float pend = 0.f;
    if (t > 0) { if (bc[0] > 1e6f || bc[1] > 1e6f) pend = 1e-5f; }

    float dp = 0.f;
    float zc[2];
    #pragma unroll
    for (int h = 0; h < 2; ++h) {
        const int i = tid + h * 256;
        const float z = fmaf(pend, u_r[h], z_r[h]);
        zs[i] = z; zc[h] = z;
        dp = fmaf(z, u_r[h], dp);
    }
    dp = wred64(dp);
    if (lane == 0) bc[2 + wid] = dp;
    __syncthreads();
    const float dot = bc[2] + bc[3] + bc[4] + bc[5];
    const float dpl = 1.f + dot;
    const bool nn = __builtin_isnan(dpl);
    const float delta = nn ? dpl : fmaxf(dpl, 1e-6f);  // jnp.maximum NaN-propagation
    const bool unst = nn || __builtin_isinf(delta) || (fabsf(delta) < 1e-6f);
    const float subc = unst ? 0.f : (1.f / delta);
    const float d12 = (unst ? 1e-6f : 0.f) + ((((t + 1) & 127) == 0) ? 1e-6f : 0.f);
    const float coef = 1.f - subc * dot;   // z2 = coef*z + d12*u
    const float sv_ = sseq[b * TT + t];
    #pragma unroll
    for (int h = 0; h < 2; ++h) {
        const int i = tid + h * 256;
        al[i] = sv_ * (coef * zc[h] + d12 * u_r[h]);
    }
    __syncthreads();

    const float dadd = pend + d12;
    float na = 0.f, ns = 0.f;
    const float4* zs4 = (const float4*)zs;
    const float4* un4 = (const float4*)un;
    const float4* al4 = (const float4*)al;
    const float4* qs4 = (const float4*)qs;

    // A pass: A += pend*I ; A -= (z z^T)/delta ; A += d12*I ; fuse ||A||^2 and z_{t+1}=A u_{t+1}
    #pragma unroll
    for (int r = 0; r < 2; ++r) {
        const int grow = slab * 8 + wid * 2 + r;
        const float zr = zs[grow];
        const float Cz = subc * zr;
        float4* Arow = (float4*)(A + ((size_t)(b * DD + grow)) * DD);
        float znp = 0.f;
        #pragma unroll
        for (int c = 0; c < 2; ++c) {
            const int idx = c * 64 + lane;
            float4 a = Arow[idx];
            const float4 zv = zs4[idx];
            const float4 uv = un4[idx];
            const int jb = idx * 4;
            a.x = fmaf(-Cz, zv.x, a.x) + ((jb + 0 == grow) ? dadd : 0.f);
            a.y = fmaf(-Cz, zv.y, a.y) + ((jb + 1 == grow) ? dadd : 0.f);
            a.z = fmaf(-Cz, zv.z, a.z) + ((jb + 2 == grow) ? dadd : 0.f);
            a.w = fmaf(-Cz, zv.w, a.w) + ((jb + 3 == grow) ? dadd : 0.f);
            na += a.x * a.x + a.y * a.y + a.z * a.z + a.w * a.w;
            znp += a.x * uv.x + a.y * uv.y + a.z * uv.z + a.w * uv.w;
            Arow[idx] = a;
        }
        znp = wred64(znp);
        if (lane == 0) zbuf[(size_t)nxt * (BB * DD) + b * DD + grow] = znp;
    }
    // S pass: S += vn*alpha^T ; fuse ||S||^2 and o = S_new q
    #pragma unroll
    for (int r = 0; r < 2; ++r) {
        const int grow = slab * 8 + wid * 2 + r;
        const float vr = bf2f(Vnb[rowbase + grow]);
        float4* Srow = (float4*)(S + ((size_t)(b * DD + grow)) * DD);
        float op = 0.f;
        #pragma unroll
        for (int c = 0; c < 2; ++c) {
            const int idx = c * 64 + lane;
            float4 s4 = Srow[idx];
            const float4 av = al4[idx];
            const float4 qv = qs4[idx];
            s4.x = fmaf(vr, av.x, s4.x);
            s4.y = fmaf(vr, av.y, s4.y);
            s4.z = fmaf(vr, av.z, s4.z);
            s4.w = fmaf(vr, av.w, s4.w);
            ns += s4.x * s4.x + s4.y * s4.y + s4.z * s4.z + s4.w * s4.w;
            op += s4.x * qv.x + s4.y * qv.y + s4.z * qv.z + s4.w * qv.w;
            Srow[idx] = s4;
        }
        op = wred64(op);
        if (lane == 0) Ob[rowbase + grow] = f2bf(op);
    }
    na = wred64(na); ns = wred64(ns);
    if (lane == 0) { rA[wid] = na; rS[wid] = ns; }
    __syncthreads();
    if (tid == 0) {
        nrm[((size_t)cur * 2 + 0) * (BB * GG) + b * GG + slab] = rA[0] + rA[1] + rA[2] + rA[3];
        nrm[((size_t)cur * 2 + 1) * (BB * GG) + b * GG + slab] = rS[0] + rS[1] + rS[2] + rS[3];
    }
}

extern "C" void kernel_launch(void* const* d_in, const int* in_sizes, int n_in,
                              void* d_out, int out_size, void* d_ws, size_t ws_size,
                              hipStream_t stream)
{
    const float* x  = (const float*)d_in[0];
    const float* Wq = (const float*)d_in[1];
    const float* bq = (const float*)d_in[2];
    const float* Wk = (const float*)d_in[3];
    const float* bk = (const float*)d_in[4];
    const float* Wv = (const float*)d_in[5];
    const float* bv = (const float*)d_in[6];
    const float* Wo = (const float*)d_in[7];
    const float* bo = (const float*)d_in[8];

    char* ws = (char*)d_ws;
    u16* Qb   = (u16*)(ws);                      // 16 MiB  Q bf16
    u16* Ub   = (u16*)(ws + (16u << 20));        // 16 MiB  U = K/sqrt(512) bf16
    u16* Vnb  = (u16*)(ws + (32u << 20));        // 16 MiB  V -> Vn bf16 (in place)
    u16* Ob   = (u16*)(ws + (48u << 20));        // 16 MiB  O bf16
    float* A  = (float*)(ws + (64u << 20));      // 8 MiB
    float* S  = (float*)(ws + (72u << 20));      // 8 MiB
    float* zbuf = (float*)(ws + (80u << 20));            // 32 KiB [2][B][512]
    float* nrm  = (float*)(ws + (80u << 20) + 32768);    // 16 KiB [2][2][B][GG]
    float* sseq = (float*)(ws + (80u << 20) + 65536);    // 64 KiB [B*T]

    dim3 gg(16384 / 64, 512 / 64);
    gemm_xwT<0, 1><<<gg, 256, 0, stream>>>(x, Wq, bq, Qb, 512, 1.f);
    gemm_xwT<0, 1><<<gg, 256, 0, stream>>>(x, Wk, bk, Ub, 512, 0.04419417382415922f);
    gemm_xwT<0, 1><<<gg, 256, 0, stream>>>(x, Wv, bv, Vnb, 512, 1.f);
    prep_kernel<<<4096, 256, 0, stream>>>(Qb, Ub, Vnb, sseq);
    init_kernel<<<1024, 256, 0, stream>>>((float4*)A, (float4*)S, zbuf, Ub);
    for (int t = 0; t < TT; ++t)
        step_kernel<<<512, 256, 0, stream>>>(t, Qb, Ub, Vnb, sseq, A, S, zbuf, nrm, Ob);
    gemm_xwT<1, 0><<<gg, 256, 0, stream>>>(Ob, Wo, bo, d_out, 512, 1.f);
}